// Round 1
// baseline (15354.800 us; speedup 1.0000x reference)
//
#include <hip/hip_runtime.h>

#define T_STEPS 2048
#define BATCH   32
#define IDIM    256
#define HDIM    512
#define NWG     32     // one WG per 16 h-indices (x4 gates = 64 cols)
#define NTHR    256    // 4 waves
#define KKX     8      // k-tiles (of 32) for x part
#define KKTOT   24     // 8 (x) + 16 (h)
#define KKW     6      // k-tiles per wave (K-split)

typedef __attribute__((ext_vector_type(8))) short bfrag;   // 8 x bf16
typedef __attribute__((ext_vector_type(4))) float facc;    // 4 x f32

__device__ __forceinline__ unsigned short f2bf(float f) {
    unsigned u = __builtin_bit_cast(unsigned, f);
    u += 0x7FFFu + ((u >> 16) & 1u);          // RNE
    return (unsigned short)(u >> 16);
}
__device__ __forceinline__ unsigned pack2(float a, float b) {
    return (unsigned)f2bf(a) | ((unsigned)f2bf(b) << 16);
}

__global__ __launch_bounds__(NTHR, 1) void lstm_persist(
    const float* __restrict__ x,      // [T,B,I]
    const float* __restrict__ tim,    // [T,B,1]
    const float* __restrict__ Wih,    // [4H, I+1]
    const float* __restrict__ Whh,    // [4H, H]
    const float* __restrict__ bias,   // [4H]
    const float* __restrict__ h0,     // [B,H]
    const float* __restrict__ c0,     // [B,H]
    float* __restrict__ out,          // [T,B,H] ++ [B,H] ++ [B,H]
    unsigned* __restrict__ flags,     // [NWG], zeroed on-stream before launch
    unsigned short* __restrict__ hbuf)// [2][B][H] bf16 double buffer
{
    const int tid  = threadIdx.x;
    const int wg   = blockIdx.x;
    const int wv   = tid >> 6;
    const int lane = tid & 63;
    const int l15  = lane & 15;
    const int kgrp = lane >> 4;

    __shared__ uint4 af[KKTOT * 2 * 64];    // 48 KB: A fragments [kk][m][lane]
    __shared__ float zpart[4 * BATCH * 64]; // 32 KB: per-wave K-split partials
    __shared__ float cbuf[BATCH * 16];      // persistent c state (our 16 h-idx)
    __shared__ float timebuf[BATCH];
    __shared__ float biasbuf[64];
    __shared__ float wtbuf[64];

    // ---- preload weights (B operand) into registers; K split across waves ----
    // B frag for (n, kkl): lane holds W[col = gate n, h-idx wg*16+(lane&15)][k0 + kgrp*8 + j]
    bfrag breg[4][KKW];
#pragma unroll
    for (int n = 0; n < 4; ++n) {
        const int colg = n * HDIM + wg * 16 + l15;
#pragma unroll
        for (int kkl = 0; kkl < KKW; ++kkl) {
            const int kk = wv * KKW + kkl;
            const float* src = (kk < KKX)
                ? (Wih + (size_t)colg * (IDIM + 1) + kk * 32 + kgrp * 8)
                : (Whh + (size_t)colg * HDIM + (kk - KKX) * 32 + kgrp * 8);
            bfrag v;
#pragma unroll
            for (int j = 0; j < 8; ++j) v[j] = (short)f2bf(src[j]);
            breg[n][kkl] = v;
        }
    }

    if (tid < 64) {
        const int colg = (tid >> 4) * HDIM + wg * 16 + (tid & 15);
        biasbuf[tid] = bias[colg];
        wtbuf[tid]   = Wih[(size_t)colg * (IDIM + 1) + IDIM];  // dt column
    }

    // ---- init c state; publish h_state[0] (our slice) into hbuf[0] ----
#pragma unroll
    for (int i = 0; i < 2; ++i) {
        const int p = i * NTHR + tid;           // 0..511
        const int b = p >> 4, idx = p & 15;
        const int col = wg * 16 + idx;
        cbuf[p] = c0[b * HDIM + col];
        hbuf[b * HDIM + col] = f2bf(h0[b * HDIM + col]);
    }
    __builtin_amdgcn_fence(__ATOMIC_RELEASE, "agent");
    __syncthreads();
    if (tid == 0)
        __hip_atomic_store(&flags[wg], 1u, __ATOMIC_RELAXED, __HIP_MEMORY_SCOPE_AGENT);

    for (int t = 0; t < T_STEPS; ++t) {
        // ---- stage x fragments + time (independent of h -> before the poll) ----
#pragma unroll
        for (int i = 0; i < 4; ++i) {
            const int c = i * NTHR + tid;       // 1024 chunks
            const int kk = c >> 7, m = (c >> 6) & 1, ln = c & 63;
            const int row = (ln & 15) + 16 * m;
            const int kx = kk * 32 + (ln >> 4) * 8;
            const float4* p4 = reinterpret_cast<const float4*>(
                x + ((size_t)t * BATCH + row) * IDIM + kx);
            const float4 f0 = p4[0], f1 = p4[1];
            uint4 v;
            v.x = pack2(f0.x, f0.y); v.y = pack2(f0.z, f0.w);
            v.z = pack2(f1.x, f1.y); v.w = pack2(f1.z, f1.w);
            af[(kk * 2 + m) * 64 + ln] = v;
        }
        if (tid < BATCH) timebuf[tid] = tim[t * BATCH + tid];

        // ---- wait for h_state[t] from all producers ----
        if (tid < NWG) {
            while (__hip_atomic_load(&flags[tid], __ATOMIC_RELAXED,
                                     __HIP_MEMORY_SCOPE_AGENT) < (unsigned)(t + 1)) {}
        }
        __syncthreads();                                   // SYNC_A
        __builtin_amdgcn_fence(__ATOMIC_ACQUIRE, "agent");

        // ---- stage h fragments from hbuf[t&1] ----
        const unsigned short* hcur = hbuf + (size_t)(t & 1) * BATCH * HDIM;
#pragma unroll
        for (int i = 0; i < 8; ++i) {
            const int c = i * NTHR + tid;       // 2048 chunks
            const int kk8 = c >> 7, m = (c >> 6) & 1, ln = c & 63;
            const int row = (ln & 15) + 16 * m;
            const int kh = kk8 * 32 + (ln >> 4) * 8;
            af[((KKX + kk8) * 2 + m) * 64 + ln] =
                *reinterpret_cast<const uint4*>(hcur + row * HDIM + kh);
        }
        __syncthreads();                                   // SYNC_B

        // ---- GEMM: z-partials, K-split across waves, B from registers ----
        const facc z4 = {0.f, 0.f, 0.f, 0.f};
        facc acc[2][4];
#pragma unroll
        for (int m = 0; m < 2; ++m)
#pragma unroll
            for (int n = 0; n < 4; ++n) acc[m][n] = z4;
#pragma unroll
        for (int kkl = 0; kkl < KKW; ++kkl) {
            const int kk = wv * KKW + kkl;
            const bfrag a0 = *reinterpret_cast<const bfrag*>(&af[(kk * 2 + 0) * 64 + lane]);
            const bfrag a1 = *reinterpret_cast<const bfrag*>(&af[(kk * 2 + 1) * 64 + lane]);
#pragma unroll
            for (int n = 0; n < 4; ++n) {
                acc[0][n] = __builtin_amdgcn_mfma_f32_16x16x32_bf16(a0, breg[n][kkl], acc[0][n], 0, 0, 0);
                acc[1][n] = __builtin_amdgcn_mfma_f32_16x16x32_bf16(a1, breg[n][kkl], acc[1][n], 0, 0, 0);
            }
        }
        // D layout: col = lane&15, row = (lane>>4)*4 + r (+16*m)   [m89-verified]
#pragma unroll
        for (int m = 0; m < 2; ++m)
#pragma unroll
            for (int n = 0; n < 4; ++n)
#pragma unroll
                for (int r = 0; r < 4; ++r)
                    zpart[((wv * BATCH) + m * 16 + kgrp * 4 + r) * 64 + n * 16 + l15] = acc[m][n][r];
        __syncthreads();                                   // SYNC_C

        // ---- gates + state update; publish h_state[t+1] ----
        unsigned short* hnext = hbuf + (size_t)((t + 1) & 1) * BATCH * HDIM;
#pragma unroll
        for (int i = 0; i < 2; ++i) {
            const int p = i * NTHR + tid;       // 0..511  (b, idx)
            const int b = p >> 4, idx = p & 15;
            float z[4];
#pragma unroll
            for (int g = 0; g < 4; ++g) {
                float s = biasbuf[g * 16 + idx] + wtbuf[g * 16 + idx] * timebuf[b];
#pragma unroll
                for (int w2 = 0; w2 < 4; ++w2)
                    s += zpart[(w2 * BATCH + b) * 64 + g * 16 + idx];
                z[g] = s;
            }
            const float ig = 1.f / (1.f + __expf(-z[0]));
            const float fg = 1.f / (1.f + __expf(-z[1]));
            const float e2g = __expf(2.f * z[2]);
            const float gg = 1.f - 2.f / (e2g + 1.f);      // tanh
            const float og = 1.f / (1.f + __expf(-z[3]));
            const float cn = fg * cbuf[p] + ig * gg;
            cbuf[p] = cn;
            const float e2c = __expf(2.f * cn);
            const float th = 1.f - 2.f / (e2c + 1.f);      // tanh
            const float hn = og * th;
            const int col = wg * 16 + idx;
            out[((size_t)t * BATCH + b) * HDIM + col] = hn;
            hnext[b * HDIM + col] = f2bf(hn);
            if (t == T_STEPS - 1) {
                out[(size_t)T_STEPS * BATCH * HDIM + (size_t)b * HDIM + col] = hn;
                out[(size_t)T_STEPS * BATCH * HDIM + (size_t)BATCH * HDIM + (size_t)b * HDIM + col] = cn;
            }
        }
        __builtin_amdgcn_fence(__ATOMIC_RELEASE, "agent");
        __syncthreads();                                   // SYNC_D
        if (tid == 0)
            __hip_atomic_store(&flags[wg], (unsigned)(t + 2), __ATOMIC_RELAXED, __HIP_MEMORY_SCOPE_AGENT);
    }
}

extern "C" void kernel_launch(void* const* d_in, const int* in_sizes, int n_in,
                              void* d_out, int out_size, void* d_ws, size_t ws_size,
                              hipStream_t stream) {
    const float* x    = (const float*)d_in[0];
    const float* tim  = (const float*)d_in[1];
    const float* Wih  = (const float*)d_in[2];
    const float* Whh  = (const float*)d_in[3];
    const float* bias = (const float*)d_in[4];
    const float* h0   = (const float*)d_in[5];
    const float* c0   = (const float*)d_in[6];

    unsigned*       flags = (unsigned*)d_ws;
    unsigned short* hbuf  = (unsigned short*)((char*)d_ws + 256);

    // flags must start at 0 every call (graph replays don't re-poison)
    hipMemsetAsync(d_ws, 0, 256, stream);

    lstm_persist<<<NWG, NTHR, 0, stream>>>(x, tim, Wih, Whh, bias, h0, c0,
                                           (float*)d_out, flags, hbuf);
}

// Round 2
// 14546.368 us; speedup vs baseline: 1.0556x; 1.0556x over previous
//
#include <hip/hip_runtime.h>

#define T_STEPS 2048
#define BATCH   32
#define IDIM    256
#define HDIM    512
#define NWG     32     // one WG per 16 h-indices (x4 gates = 64 gate cols)
#define NTHR    256    // 4 waves; wave wv owns gate wv (N-split, full K per wave)
#define KKX     8      // k-tiles (of 32) for x part
#define KKTOT   24     // 8 (x) + 16 (h)

typedef __attribute__((ext_vector_type(8))) short bfrag;   // 8 x bf16
typedef __attribute__((ext_vector_type(4))) float facc;    // 4 x f32

#define LD_AGENT(p)    __hip_atomic_load((p),  __ATOMIC_RELAXED, __HIP_MEMORY_SCOPE_AGENT)
#define ST_AGENT(p, v) __hip_atomic_store((p), (v), __ATOMIC_RELAXED, __HIP_MEMORY_SCOPE_AGENT)

__device__ __forceinline__ unsigned short f2bf(float f) {
    unsigned u = __builtin_bit_cast(unsigned, f);
    u += 0x7FFFu + ((u >> 16) & 1u);          // RNE
    return (unsigned short)(u >> 16);
}
__device__ __forceinline__ unsigned pack2(float a, float b) {
    return (unsigned)f2bf(a) | ((unsigned)f2bf(b) << 16);
}

// Coherence protocol (no cache-maintenance fences!):
//  - h exchange + flags live in d_ws; ALL accesses to them are relaxed
//    agent-scope atomics (sc-bit per-access coherent, bypass stale L1/L2).
//  - producer: hbuf stores -> s_waitcnt vmcnt(0) (per wave) -> __syncthreads
//    -> tid0 stores flag. Consumer: poll flag -> __syncthreads -> hbuf loads.
//  - `out` is written AFTER the flag publish: host-only data, kernel-end
//    flush makes it visible; keeps HBM store completion off the critical path.
__global__ __launch_bounds__(NTHR, 1) void lstm_persist(
    const float* __restrict__ x,      // [T,B,I]
    const float* __restrict__ tim,    // [T,B,1]
    const float* __restrict__ Wih,    // [4H, I+1]
    const float* __restrict__ Whh,    // [4H, H]
    const float* __restrict__ bias,   // [4H]
    const float* __restrict__ h0,     // [B,H]
    const float* __restrict__ c0,     // [B,H]
    float* __restrict__ out,          // [T,B,H] ++ [B,H] ++ [B,H]
    unsigned* __restrict__ flags,     // [NWG], zeroed on-stream before launch
    unsigned* __restrict__ hbuf)      // [2][B][H/2] bf16-pair double buffer
{
    const int tid  = threadIdx.x;
    const int wg   = blockIdx.x;
    const int wv   = tid >> 6;
    const int lane = tid & 63;
    const int l15  = lane & 15;
    const int kgrp = lane >> 4;

    __shared__ uint4 af[KKTOT * 2 * 64];    // 48 KB: A fragments [kk][m][lane]
    __shared__ float zfull[BATCH * 64];     // 8 KB: z for our 64 gate cols
    __shared__ float timebuf[BATCH];
    __shared__ float biasbuf[64];
    __shared__ float wtbuf[64];

    // ---- weights (B operand) in registers: wave wv = gate wv, full K ----
    bfrag breg[KKTOT];
    {
        const int colg = wv * HDIM + wg * 16 + l15;
#pragma unroll
        for (int j = 0; j < KKTOT; ++j) {
            const float* src = (j < KKX)
                ? (Wih + (size_t)colg * (IDIM + 1) + j * 32 + kgrp * 8)
                : (Whh + (size_t)colg * HDIM + (j - KKX) * 32 + kgrp * 8);
            bfrag v;
#pragma unroll
            for (int jj = 0; jj < 8; ++jj) v[jj] = (short)f2bf(src[jj]);
            breg[j] = v;
        }
    }
    if (tid < 64) {
        const int cg = (tid >> 4) * HDIM + wg * 16 + (tid & 15);
        biasbuf[tid] = bias[cg];
        wtbuf[tid]   = Wih[(size_t)cg * (IDIM + 1) + IDIM];   // dt column
    }

    // ---- per-thread gate item: (b, idx0), idx0 even; c state in registers ----
    const int gb    = tid >> 3;
    const int gidx0 = (tid & 7) * 2;
    const int gcol0 = wg * 16 + gidx0;
    float creg0 = c0[gb * HDIM + gcol0];
    float creg1 = c0[gb * HDIM + gcol0 + 1];

    // publish h0 slice (coherent)
    ST_AGENT(hbuf + gb * (HDIM / 2) + (gcol0 >> 1),
             pack2(h0[gb * HDIM + gcol0], h0[gb * HDIM + gcol0 + 1]));
    asm volatile("s_waitcnt vmcnt(0)" ::: "memory");
    __syncthreads();
    if (tid == 0) ST_AGENT(&flags[wg], 1u);

    for (int t = 0; t < T_STEPS; ++t) {
        // ---- stage x fragments + time (independent of h) ----
#pragma unroll
        for (int i = 0; i < 4; ++i) {
            const int c = i * NTHR + tid;       // 1024 chunks
            const int kk = c >> 7, m = (c >> 6) & 1, ln = c & 63;
            const int row = (ln & 15) + 16 * m;
            const int kx = kk * 32 + (ln >> 4) * 8;
            const float4* p4 = reinterpret_cast<const float4*>(
                x + ((size_t)t * BATCH + row) * IDIM + kx);
            const float4 f0 = p4[0], f1 = p4[1];
            uint4 v;
            v.x = pack2(f0.x, f0.y); v.y = pack2(f0.z, f0.w);
            v.z = pack2(f1.x, f1.y); v.w = pack2(f1.z, f1.w);
            af[(kk * 2 + m) * 64 + ln] = v;
        }
        if (tid < BATCH) timebuf[tid] = tim[t * BATCH + tid];
        __syncthreads();                                   // SYNC_X

        // ---- x-part GEMM while h_t may still be in flight ----
        facc acc0 = {0.f, 0.f, 0.f, 0.f};
        facc acc1 = {0.f, 0.f, 0.f, 0.f};
#pragma unroll
        for (int j = 0; j < KKX; ++j) {
            const bfrag a0 = *reinterpret_cast<const bfrag*>(&af[(j * 2 + 0) * 64 + lane]);
            const bfrag a1 = *reinterpret_cast<const bfrag*>(&af[(j * 2 + 1) * 64 + lane]);
            acc0 = __builtin_amdgcn_mfma_f32_16x16x32_bf16(a0, breg[j], acc0, 0, 0, 0);
            acc1 = __builtin_amdgcn_mfma_f32_16x16x32_bf16(a1, breg[j], acc1, 0, 0, 0);
        }

        // ---- wait for h_state[t] from all producers ----
        if (tid < NWG) {
            while (LD_AGENT(&flags[tid]) < (unsigned)(t + 1)) {}
        }
        __syncthreads();                                   // SYNC_A

        // ---- stage h fragments from hbuf[t&1] (coherent dword loads) ----
        const unsigned* hcur = hbuf + (size_t)(t & 1) * BATCH * (HDIM / 2);
#pragma unroll
        for (int i = 0; i < 8; ++i) {
            const int c = i * NTHR + tid;       // 2048 chunks
            const int kk8 = c >> 7, m = (c >> 6) & 1, ln = c & 63;
            const int row = (ln & 15) + 16 * m;
            const unsigned* s = hcur + row * (HDIM / 2) + kk8 * 16 + (ln >> 4) * 4;
            uint4 v;
            v.x = LD_AGENT(s + 0); v.y = LD_AGENT(s + 1);
            v.z = LD_AGENT(s + 2); v.w = LD_AGENT(s + 3);
            af[((KKX + kk8) * 2 + m) * 64 + ln] = v;
        }
        __syncthreads();                                   // SYNC_B

        // ---- h-part GEMM ----
#pragma unroll
        for (int j = KKX; j < KKTOT; ++j) {
            const bfrag a0 = *reinterpret_cast<const bfrag*>(&af[(j * 2 + 0) * 64 + lane]);
            const bfrag a1 = *reinterpret_cast<const bfrag*>(&af[(j * 2 + 1) * 64 + lane]);
            acc0 = __builtin_amdgcn_mfma_f32_16x16x32_bf16(a0, breg[j], acc0, 0, 0, 0);
            acc1 = __builtin_amdgcn_mfma_f32_16x16x32_bf16(a1, breg[j], acc1, 0, 0, 0);
        }
        // D layout: col = lane&15, row = (lane>>4)*4 + r (+16*m)
#pragma unroll
        for (int r = 0; r < 4; ++r) {
            zfull[(kgrp * 4 + r) * 64      + wv * 16 + l15] = acc0[r];
            zfull[(16 + kgrp * 4 + r) * 64 + wv * 16 + l15] = acc1[r];
        }
        __syncthreads();                                   // SYNC_C

        // ---- gates + state update; publish h_state[t+1] ----
        float z0[4], z1[4];
#pragma unroll
        for (int g = 0; g < 4; ++g) {
            const float tb = timebuf[gb];
            z0[g] = biasbuf[g * 16 + gidx0]     + wtbuf[g * 16 + gidx0]     * tb
                  + zfull[gb * 64 + g * 16 + gidx0];
            z1[g] = biasbuf[g * 16 + gidx0 + 1] + wtbuf[g * 16 + gidx0 + 1] * tb
                  + zfull[gb * 64 + g * 16 + gidx0 + 1];
        }
        float hn0, hn1;
        {
            const float ig = 1.f / (1.f + __expf(-z0[0]));
            const float fg = 1.f / (1.f + __expf(-z0[1]));
            const float gg = 1.f - 2.f / (__expf(2.f * z0[2]) + 1.f);
            const float og = 1.f / (1.f + __expf(-z0[3]));
            creg0 = fg * creg0 + ig * gg;
            hn0 = og * (1.f - 2.f / (__expf(2.f * creg0) + 1.f));
        }
        {
            const float ig = 1.f / (1.f + __expf(-z1[0]));
            const float fg = 1.f / (1.f + __expf(-z1[1]));
            const float gg = 1.f - 2.f / (__expf(2.f * z1[2]) + 1.f);
            const float og = 1.f / (1.f + __expf(-z1[3]));
            creg1 = fg * creg1 + ig * gg;
            hn1 = og * (1.f - 2.f / (__expf(2.f * creg1) + 1.f));
        }
        unsigned* hnext = hbuf + (size_t)((t + 1) & 1) * BATCH * (HDIM / 2);
        ST_AGENT(hnext + gb * (HDIM / 2) + (gcol0 >> 1), pack2(hn0, hn1));
        asm volatile("s_waitcnt vmcnt(0)" ::: "memory");
        __syncthreads();                                   // SYNC_D
        if (tid == 0) ST_AGENT(&flags[wg], (unsigned)(t + 2));

        // ---- out stores AFTER the publish (off critical path) ----
        *reinterpret_cast<float2*>(&out[((size_t)t * BATCH + gb) * HDIM + gcol0]) =
            make_float2(hn0, hn1);
        if (t == T_STEPS - 1) {
            float* hT = out + (size_t)T_STEPS * BATCH * HDIM;
            float* cT = hT + (size_t)BATCH * HDIM;
            *reinterpret_cast<float2*>(&hT[(size_t)gb * HDIM + gcol0]) = make_float2(hn0, hn1);
            *reinterpret_cast<float2*>(&cT[(size_t)gb * HDIM + gcol0]) = make_float2(creg0, creg1);
        }
    }
}

extern "C" void kernel_launch(void* const* d_in, const int* in_sizes, int n_in,
                              void* d_out, int out_size, void* d_ws, size_t ws_size,
                              hipStream_t stream) {
    const float* x    = (const float*)d_in[0];
    const float* tim  = (const float*)d_in[1];
    const float* Wih  = (const float*)d_in[2];
    const float* Whh  = (const float*)d_in[3];
    const float* bias = (const float*)d_in[4];
    const float* h0   = (const float*)d_in[5];
    const float* c0   = (const float*)d_in[6];

    unsigned* flags = (unsigned*)d_ws;
    unsigned* hbuf  = (unsigned*)((char*)d_ws + 256);

    // flags must start at 0 every call (graph replays don't re-poison)
    hipMemsetAsync(d_ws, 0, 256, stream);

    lstm_persist<<<NWG, NTHR, 0, stream>>>(x, tim, Wih, Whh, bias, h0, c0,
                                           (float*)d_out, flags, hbuf);
}

// Round 3
// 13265.822 us; speedup vs baseline: 1.1575x; 1.0965x over previous
//
#include <hip/hip_runtime.h>

#define T_STEPS 2048
#define BATCH   32
#define IDIM    256
#define HDIM    512
#define NWG     32     // one WG per 16 h-indices (x4 gates = 64 gate cols)
#define NTHR    256    // 4 waves; wave wv owns gate wv (N-split, full K per wave)
#define KKX     8      // k-tiles (of 32) for x part
#define KKTOT   24     // 8 (x) + 16 (h)

typedef __attribute__((ext_vector_type(8))) short bfrag;   // 8 x bf16
typedef __attribute__((ext_vector_type(4))) float facc;    // 4 x f32
typedef unsigned long long u64;

#define LD_AGENT64(p)    __hip_atomic_load((p),  __ATOMIC_RELAXED, __HIP_MEMORY_SCOPE_AGENT)
#define ST_AGENT64(p, v) __hip_atomic_store((p), (v), __ATOMIC_RELAXED, __HIP_MEMORY_SCOPE_AGENT)

__device__ __forceinline__ unsigned short f2bf(float f) {
    unsigned u = __builtin_bit_cast(unsigned, f);
    u += 0x7FFFu + ((u >> 16) & 1u);          // RNE
    return (unsigned short)(u >> 16);
}
__device__ __forceinline__ unsigned pack2(float a, float b) {
    return (unsigned)f2bf(a) | ((unsigned)f2bf(b) << 16);
}

// Sync protocol: SELF-TIMESTAMPED h exchange, ONE L3 round trip per step.
//  - hbuf is [2][B][H/2] of u64 words: low 32 = 2 packed bf16, high 32 = tag.
//  - h_state[s] (s = steps completed) lives in buf[s&1] with tag s+1.
//  - Consumer at step t loads its words from buf[t&1] and retries any word
//    whose tag != t+1. Per-word 8B atomicity makes each word self-validating:
//    no flags, no polls, no release drains, no fences.
//  - Overwrite safety: h(t+2) lands in buf[t&1] only after ALL WGs published
//    h(t+1), which requires each to have finished READING h(t) from that
//    buffer. So a wanted tag is never destroyed before it is consumed.
//  - hbuf is memset to 0 on-stream each launch (tag 0 never matches), so
//    graph replays are deterministic.
//  - `out` stores happen AFTER the publish: host-only data, off critical path.
__global__ __launch_bounds__(NTHR, 1) void lstm_persist(
    const float* __restrict__ x,      // [T,B,I]
    const float* __restrict__ tim,    // [T,B,1]
    const float* __restrict__ Wih,    // [4H, I+1]
    const float* __restrict__ Whh,    // [4H, H]
    const float* __restrict__ bias,   // [4H]
    const float* __restrict__ h0,     // [B,H]
    const float* __restrict__ c0,     // [B,H]
    float* __restrict__ out,          // [T,B,H] ++ [B,H] ++ [B,H]
    u64* __restrict__ hbuf)           // [2][B][H/2] tagged bf16-pair words
{
    const int tid  = threadIdx.x;
    const int wg   = blockIdx.x;
    const int wv   = tid >> 6;
    const int lane = tid & 63;
    const int l15  = lane & 15;
    const int kgrp = lane >> 4;

    __shared__ uint4 af[KKTOT * 2 * 64];    // 48 KB: A fragments [kk][m][lane]
    __shared__ float zfull[BATCH * 64];     // 8 KB: z for our 64 gate cols
    __shared__ float timebuf[BATCH];
    __shared__ float biasbuf[64];
    __shared__ float wtbuf[64];

    // ---- weights (B operand) in registers: wave wv = gate wv, full K ----
    bfrag breg[KKTOT];
    {
        const int colg = wv * HDIM + wg * 16 + l15;
#pragma unroll
        for (int j = 0; j < KKTOT; ++j) {
            const float* src = (j < KKX)
                ? (Wih + (size_t)colg * (IDIM + 1) + j * 32 + kgrp * 8)
                : (Whh + (size_t)colg * HDIM + (j - KKX) * 32 + kgrp * 8);
            bfrag v;
#pragma unroll
            for (int jj = 0; jj < 8; ++jj) v[jj] = (short)f2bf(src[jj]);
            breg[j] = v;
        }
    }
    if (tid < 64) {
        const int cg = (tid >> 4) * HDIM + wg * 16 + (tid & 15);
        biasbuf[tid] = bias[cg];
        wtbuf[tid]   = Wih[(size_t)cg * (IDIM + 1) + IDIM];   // dt column
    }

    // ---- per-thread gate item: (b, idx0), idx0 even; c state in registers ----
    const int gb    = tid >> 3;
    const int gidx0 = (tid & 7) * 2;
    const int gcol0 = wg * 16 + gidx0;
    float creg0 = c0[gb * HDIM + gcol0];
    float creg1 = c0[gb * HDIM + gcol0 + 1];

    // publish h0 slice: tag 1, buf[0] — no drain, no flag
    ST_AGENT64(hbuf + gb * (HDIM / 2) + (gcol0 >> 1),
               (1ULL << 32) | (u64)pack2(h0[gb * HDIM + gcol0],
                                         h0[gb * HDIM + gcol0 + 1]));

    // consumer-side constants (each thread reads 8 chunks of 4 words, 1 row)
    const int hm   = (tid >> 6) & 1;
    const int hrow = (tid & 15) + 16 * hm;
    const int hoff = hrow * (HDIM / 2) + (tid >> 7) * 16 + ((tid & 63) >> 4) * 4;

    for (int t = 0; t < T_STEPS; ++t) {
        // ---- stage x fragments + time (independent of h) ----
#pragma unroll
        for (int i = 0; i < 4; ++i) {
            const int c = i * NTHR + tid;       // 1024 chunks
            const int kk = c >> 7, m = (c >> 6) & 1, ln = c & 63;
            const int row = (ln & 15) + 16 * m;
            const int kx = kk * 32 + (ln >> 4) * 8;
            const float4* p4 = reinterpret_cast<const float4*>(
                x + ((size_t)t * BATCH + row) * IDIM + kx);
            const float4 f0 = p4[0], f1 = p4[1];
            uint4 v;
            v.x = pack2(f0.x, f0.y); v.y = pack2(f0.z, f0.w);
            v.z = pack2(f1.x, f1.y); v.w = pack2(f1.z, f1.w);
            af[(kk * 2 + m) * 64 + ln] = v;
        }
        if (tid < BATCH) timebuf[tid] = tim[t * BATCH + tid];
        __syncthreads();                                   // SYNC_X

        // ---- issue tagged h loads (overlap their latency with x-GEMM) ----
        const u64* rowp = hbuf + (size_t)(t & 1) * (BATCH * HDIM / 2) + hoff;
        u64 hw[8][4];
#pragma unroll
        for (int i = 0; i < 8; ++i)
#pragma unroll
            for (int jj = 0; jj < 4; ++jj)
                hw[i][jj] = LD_AGENT64(rowp + i * 32 + jj);

        // ---- x-part GEMM while h words are in flight ----
        facc acc0 = {0.f, 0.f, 0.f, 0.f};
        facc acc1 = {0.f, 0.f, 0.f, 0.f};
#pragma unroll
        for (int j = 0; j < KKX; ++j) {
            const bfrag a0 = *reinterpret_cast<const bfrag*>(&af[(j * 2 + 0) * 64 + lane]);
            const bfrag a1 = *reinterpret_cast<const bfrag*>(&af[(j * 2 + 1) * 64 + lane]);
            acc0 = __builtin_amdgcn_mfma_f32_16x16x32_bf16(a0, breg[j], acc0, 0, 0, 0);
            acc1 = __builtin_amdgcn_mfma_f32_16x16x32_bf16(a1, breg[j], acc1, 0, 0, 0);
        }

        // ---- tag check + retry (the ONLY wait in the step) ----
        const unsigned want = (unsigned)(t + 1);
        while (true) {
            bool ok = true;
#pragma unroll
            for (int i = 0; i < 8; ++i)
#pragma unroll
                for (int jj = 0; jj < 4; ++jj)
                    ok &= ((unsigned)(hw[i][jj] >> 32) == want);
            if (ok) break;
#pragma unroll
            for (int i = 0; i < 8; ++i)
#pragma unroll
                for (int jj = 0; jj < 4; ++jj)
                    if ((unsigned)(hw[i][jj] >> 32) != want)
                        hw[i][jj] = LD_AGENT64(rowp + i * 32 + jj);
        }

        // ---- stage h fragments into LDS ----
#pragma unroll
        for (int i = 0; i < 8; ++i) {
            uint4 v;
            v.x = (unsigned)hw[i][0]; v.y = (unsigned)hw[i][1];
            v.z = (unsigned)hw[i][2]; v.w = (unsigned)hw[i][3];
            const int kk8 = 2 * i + (tid >> 7);
            af[((KKX + kk8) * 2 + hm) * 64 + (tid & 63)] = v;
        }
        __syncthreads();                                   // SYNC_B

        // ---- h-part GEMM ----
#pragma unroll
        for (int j = KKX; j < KKTOT; ++j) {
            const bfrag a0 = *reinterpret_cast<const bfrag*>(&af[(j * 2 + 0) * 64 + lane]);
            const bfrag a1 = *reinterpret_cast<const bfrag*>(&af[(j * 2 + 1) * 64 + lane]);
            acc0 = __builtin_amdgcn_mfma_f32_16x16x32_bf16(a0, breg[j], acc0, 0, 0, 0);
            acc1 = __builtin_amdgcn_mfma_f32_16x16x32_bf16(a1, breg[j], acc1, 0, 0, 0);
        }
        // D layout: col = lane&15, row = (lane>>4)*4 + r (+16*m)
#pragma unroll
        for (int r = 0; r < 4; ++r) {
            zfull[(kgrp * 4 + r) * 64      + wv * 16 + l15] = acc0[r];
            zfull[(16 + kgrp * 4 + r) * 64 + wv * 16 + l15] = acc1[r];
        }
        __syncthreads();                                   // SYNC_C

        // ---- gates + state update; publish tagged h_state[t+1] ----
        const float tb = timebuf[gb];
        float z0[4], z1[4];
#pragma unroll
        for (int g = 0; g < 4; ++g) {
            z0[g] = biasbuf[g * 16 + gidx0]     + wtbuf[g * 16 + gidx0]     * tb
                  + zfull[gb * 64 + g * 16 + gidx0];
            z1[g] = biasbuf[g * 16 + gidx0 + 1] + wtbuf[g * 16 + gidx0 + 1] * tb
                  + zfull[gb * 64 + g * 16 + gidx0 + 1];
        }
        float hn0, hn1;
        {
            const float ig = 1.f / (1.f + __expf(-z0[0]));
            const float fg = 1.f / (1.f + __expf(-z0[1]));
            const float gg = 1.f - 2.f / (__expf(2.f * z0[2]) + 1.f);
            const float og = 1.f / (1.f + __expf(-z0[3]));
            creg0 = fg * creg0 + ig * gg;
            hn0 = og * (1.f - 2.f / (__expf(2.f * creg0) + 1.f));
        }
        {
            const float ig = 1.f / (1.f + __expf(-z1[0]));
            const float fg = 1.f / (1.f + __expf(-z1[1]));
            const float gg = 1.f - 2.f / (__expf(2.f * z1[2]) + 1.f);
            const float og = 1.f / (1.f + __expf(-z1[3]));
            creg1 = fg * creg1 + ig * gg;
            hn1 = og * (1.f - 2.f / (__expf(2.f * creg1) + 1.f));
        }
        u64* hnext = hbuf + (size_t)((t + 1) & 1) * (BATCH * HDIM / 2);
        ST_AGENT64(hnext + gb * (HDIM / 2) + (gcol0 >> 1),
                   ((u64)(unsigned)(t + 2) << 32) | (u64)pack2(hn0, hn1));

        // ---- out stores AFTER the publish (off critical path) ----
        *reinterpret_cast<float2*>(&out[((size_t)t * BATCH + gb) * HDIM + gcol0]) =
            make_float2(hn0, hn1);
        if (t == T_STEPS - 1) {
            float* hT = out + (size_t)T_STEPS * BATCH * HDIM;
            float* cT = hT + (size_t)BATCH * HDIM;
            *reinterpret_cast<float2*>(&hT[(size_t)gb * HDIM + gcol0]) = make_float2(hn0, hn1);
            *reinterpret_cast<float2*>(&cT[(size_t)gb * HDIM + gcol0]) = make_float2(creg0, creg1);
        }
    }
}

extern "C" void kernel_launch(void* const* d_in, const int* in_sizes, int n_in,
                              void* d_out, int out_size, void* d_ws, size_t ws_size,
                              hipStream_t stream) {
    const float* x    = (const float*)d_in[0];
    const float* tim  = (const float*)d_in[1];
    const float* Wih  = (const float*)d_in[2];
    const float* Whh  = (const float*)d_in[3];
    const float* bias = (const float*)d_in[4];
    const float* h0   = (const float*)d_in[5];
    const float* c0   = (const float*)d_in[6];

    u64* hbuf = (u64*)d_ws;

    // tags must start != any wanted tag every call (graph replays included)
    hipMemsetAsync(d_ws, 0, 2 * BATCH * (HDIM / 2) * sizeof(u64), stream);

    lstm_persist<<<NWG, NTHR, 0, stream>>>(x, tim, Wih, Whh, bias, h0, c0,
                                           (float*)d_out, hbuf);
}

// Round 5
// 6784.745 us; speedup vs baseline: 2.2631x; 1.9552x over previous
//
#include <hip/hip_runtime.h>

#define TS    2048
#define BTOT  32
#define IDIM  256
#define HDIM  512
#define GRPS  8      // batch groups (4 batches each); WGs of a group exchange h only within the group
#define WPG   32     // WGs per group: 64 gate cols each (16 h-cols x 4 gates)
#define BPG   4
#define NTHR  256    // 4 waves; wave wv = gate wv (N-split, full K)
#define KX    8      // x k-frags (K=256)
#define KT    24     // + 16 h k-frags (K=512)
#define SROW  520    // LDS h-stage row stride in shorts (512 + 8 pad: bank-shifts rows)

typedef __attribute__((ext_vector_type(8))) short    bfrag;  // 8 bf16
typedef __attribute__((ext_vector_type(4))) float    facc;   // 4 f32
typedef unsigned long long u64;

#define LD_A64(p)   __hip_atomic_load((p),  __ATOMIC_RELAXED, __HIP_MEMORY_SCOPE_AGENT)
#define ST_A64(p,v) __hip_atomic_store((p),(v),__ATOMIC_RELAXED, __HIP_MEMORY_SCOPE_AGENT)

__device__ __forceinline__ unsigned short f2bf(float f){
    unsigned u = __builtin_bit_cast(unsigned, f);
    u += 0x7FFFu + ((u >> 16) & 1u);            // RNE
    return (unsigned short)(u >> 16);
}
__device__ __forceinline__ unsigned pack2(float a, float b){
    return (unsigned)f2bf(a) | ((unsigned)f2bf(b) << 16);
}

// Protocol (R3-proven primitives, group-local volume):
//  - hgrp = hbuf + g*2048: [2 parity][1024] u64 words; word W of parity p holds
//    h-cols {2W%512, +1} of batch W>>8 (group-local), tag = step+1 in high 32.
//  - h(s) lives in parity s&1 with tag s+1. Consumer at step t retries until
//    all its 4 words carry tag t+1. Data+tag move atomically: NO ordering
//    assumptions, no fences, no sc bits, placement-independent.
//  - Overwrite safety: h(t+2) lands in parity t&1 only after all group WGs
//    published h(t+1), which requires their reads of h(t) to have completed.
//  - x is register-resident bf16, prefetched 2 steps ahead (off critical path).
//  - out stores AFTER the publish (host-only data).
#define LSTM_STEP(Tt, XF, TPF)                                                              \
  do {                                                                                      \
    /* issue tagged h loads FIRST (longest latency), overlap with x-GEMM */                 \
    const u64* hsrc = hgrp + (size_t)((Tt) & 1) * 1024 + (size_t)tid * 4;                   \
    u64 w0 = LD_A64(hsrc + 0), w1 = LD_A64(hsrc + 1);                                       \
    u64 w2 = LD_A64(hsrc + 2), w3 = LD_A64(hsrc + 3);                                       \
    facc ze = {0.f,0.f,0.f,0.f}, zo = {0.f,0.f,0.f,0.f};                                    \
    _Pragma("unroll")                                                                       \
    for (int j = 0; j < KX; j += 2){                                                        \
      ze = __builtin_amdgcn_mfma_f32_16x16x32_bf16(XF[j],   breg[j],   ze, 0,0,0);          \
      zo = __builtin_amdgcn_mfma_f32_16x16x32_bf16(XF[j+1], breg[j+1], zo, 0,0,0);          \
    }                                                                                       \
    const unsigned want = (unsigned)(Tt) + 1u;                                              \
    while ((((unsigned)(w0 >> 32) != want) | ((unsigned)(w1 >> 32) != want) |               \
            ((unsigned)(w2 >> 32) != want) | ((unsigned)(w3 >> 32) != want)) != 0u){        \
      if ((unsigned)(w0 >> 32) != want) w0 = LD_A64(hsrc + 0);                              \
      if ((unsigned)(w1 >> 32) != want) w1 = LD_A64(hsrc + 1);                              \
      if ((unsigned)(w2 >> 32) != want) w2 = LD_A64(hsrc + 2);                              \
      if ((unsigned)(w3 >> 32) != want) w3 = LD_A64(hsrc + 3);                              \
    }                                                                                       \
    { uint4 pv; pv.x = (unsigned)w0; pv.y = (unsigned)w1;                                   \
      pv.z = (unsigned)w2; pv.w = (unsigned)w3;                                             \
      *reinterpret_cast<uint4*>(                                                            \
          reinterpret_cast<char*>(hstage) + sb * (SROW*2) + sw * 4) = pv; }                 \
    __syncthreads();                                  /* B1: h staged */                    \
    _Pragma("unroll")                                                                       \
    for (int j = 0; j < 16; j += 2){                                                        \
      const bfrag ha = *reinterpret_cast<const bfrag*>(&hstage[lb*SROW + j*32 + kgrp*8]);   \
      const bfrag hb = *reinterpret_cast<const bfrag*>(&hstage[lb*SROW + (j+1)*32 + kgrp*8]); \
      ze = __builtin_amdgcn_mfma_f32_16x16x32_bf16(ha, breg[KX+j],   ze, 0,0,0);            \
      zo = __builtin_amdgcn_mfma_f32_16x16x32_bf16(hb, breg[KX+j+1], zo, 0,0,0);            \
    }                                                                                       \
    const facc zz = ze + zo;                                                                \
    if (lane < 16){   /* D rows 0..3 = batches (rows 4..15 junk, never read) */             \
      _Pragma("unroll")                                                                     \
      for (int q = 0; q < 4; ++q) zfull[wv][q][lane] = zz[q];                               \
    }                                                                                       \
    __syncthreads();                                  /* B2: z ready */                     \
    float hn0 = 0.f, hn1 = 0.f;                                                             \
    if (gth){                                                                               \
      float zg0[4], zg1[4];                                                                 \
      _Pragma("unroll")                                                                     \
      for (int gt = 0; gt < 4; ++gt){                                                       \
        zg0[gt] = zfull[gt][b][col0]     + bs2[gt][0] + wt2[gt][0] * (TPF);                 \
        zg1[gt] = zfull[gt][b][col0 + 1] + bs2[gt][1] + wt2[gt][1] * (TPF);                 \
      }                                                                                     \
      { const float ig = 1.f/(1.f+__expf(-zg0[0]));                                         \
        const float fg = 1.f/(1.f+__expf(-zg0[1]));                                         \
        const float gg = 1.f - 2.f/(__expf(2.f*zg0[2])+1.f);                                \
        const float og = 1.f/(1.f+__expf(-zg0[3]));                                         \
        creg0 = fg*creg0 + ig*gg;                                                           \
        hn0 = og*(1.f - 2.f/(__expf(2.f*creg0)+1.f)); }                                     \
      { const float ig = 1.f/(1.f+__expf(-zg1[0]));                                         \
        const float fg = 1.f/(1.f+__expf(-zg1[1]));                                         \
        const float gg = 1.f - 2.f/(__expf(2.f*zg1[2])+1.f);                                \
        const float og = 1.f/(1.f+__expf(-zg1[3]));                                         \
        creg1 = fg*creg1 + ig*gg;                                                           \
        hn1 = og*(1.f - 2.f/(__expf(2.f*creg1)+1.f)); }                                     \
      ST_A64(hgrp + (size_t)(((Tt)+1) & 1) * 1024 + b*256 + r*8 + cp,                       \
             ((u64)((unsigned)(Tt) + 2u) << 32) | (u64)pack2(hn0, hn1));                    \
    }                                                                                       \
    /* ---- tail: off critical path ---- */                                                 \
    { const int tn = ((Tt)+2 < TS) ? ((Tt)+2) : (TS-1);                                     \
      if (ldr){                                                                             \
        _Pragma("unroll")                                                                   \
        for (int j = 0; j < KX; ++j){                                                       \
          const float4* p4 = reinterpret_cast<const float4*>(                               \
              x + ((size_t)tn*BTOT + lbg)*IDIM + j*32 + kgrp*8);                            \
          const float4 f0 = p4[0], f1 = p4[1];                                              \
          bfrag v;                                                                          \
          v[0]=(short)f2bf(f0.x); v[1]=(short)f2bf(f0.y);                                   \
          v[2]=(short)f2bf(f0.z); v[3]=(short)f2bf(f0.w);                                   \
          v[4]=(short)f2bf(f1.x); v[5]=(short)f2bf(f1.y);                                   \
          v[6]=(short)f2bf(f1.z); v[7]=(short)f2bf(f1.w);                                   \
          XF[j] = v;                                                                        \
        }                                                                                   \
      }                                                                                     \
      if (gth){                                                                             \
        (TPF) = tim[(size_t)tn*BTOT + bglob];                                               \
        *reinterpret_cast<float2*>(                                                         \
            &out[((size_t)(Tt)*BTOT + bglob)*HDIM + hcol0]) = make_float2(hn0, hn1);        \
        if ((Tt) == TS-1){                                                                  \
          float* hT = out + (size_t)TS*BTOT*HDIM;                                           \
          float* cT = hT + (size_t)BTOT*HDIM;                                               \
          *reinterpret_cast<float2*>(&hT[(size_t)bglob*HDIM + hcol0]) = make_float2(hn0, hn1); \
          *reinterpret_cast<float2*>(&cT[(size_t)bglob*HDIM + hcol0]) = make_float2(creg0, creg1); \
        }                                                                                   \
      }                                                                                     \
    }                                                                                       \
  } while(0)

__global__ __launch_bounds__(NTHR, 1) void lstm_grp(
    const float* __restrict__ x,      // [T,B,I]
    const float* __restrict__ tim,    // [T,B,1]
    const float* __restrict__ Wih,    // [4H, I+1]
    const float* __restrict__ Whh,    // [4H, H]
    const float* __restrict__ bias,   // [4H]
    const float* __restrict__ h0,     // [B,H]
    const float* __restrict__ c0,     // [B,H]
    float* __restrict__ out,          // [T,B,H] ++ [B,H] ++ [B,H]
    u64* __restrict__ hbuf)           // [GRPS][2][1024] tagged words
{
    const int tid = threadIdx.x, bid = blockIdx.x;
    const int g = bid & 7, r = bid >> 3;           // group, role (16 h-cols r*16..)
    const int wv = tid >> 6, lane = tid & 63, l15 = lane & 15, kgrp = lane >> 4;

    __shared__ unsigned short hstage[BPG * SROW];  // 4.1 KB: h rows [4][520]
    __shared__ float zfull[4][4][16];              // [gate][b][col]

    u64* hgrp = hbuf + (size_t)g * 2048;

    // ---- weights in registers: wave wv = gate wv, cols r*16+l15, full K ----
    bfrag breg[KT];
    {
        const int colg = wv * HDIM + r * 16 + l15;
        #pragma unroll
        for (int j = 0; j < KT; ++j){
            const float* src = (j < KX)
                ? (Wih + (size_t)colg * (IDIM + 1) + j * 32 + kgrp * 8)
                : (Whh + (size_t)colg * HDIM + (j - KX) * 32 + kgrp * 8);
            bfrag v;
            #pragma unroll
            for (int q = 0; q < 8; ++q) v[q] = (short)f2bf(src[q]);
            breg[j] = v;
        }
    }

    // ---- gate threads (tid<32): item (b, col0=2*cp, col0+1) ----
    const bool gth = (tid < 32);
    const int b = (tid >> 3) & 3, cp = tid & 7, col0 = cp * 2;
    const int hcol0 = r * 16 + col0, bglob = g * BPG + b;
    float bs2[4][2], wt2[4][2];
    float creg0 = 0.f, creg1 = 0.f;
    if (gth){
        #pragma unroll
        for (int gt = 0; gt < 4; ++gt){
            const size_t cg = (size_t)gt * HDIM + hcol0;
            bs2[gt][0] = bias[cg];     bs2[gt][1] = bias[cg + 1];
            wt2[gt][0] = Wih[cg * (IDIM + 1) + IDIM];
            wt2[gt][1] = Wih[(cg + 1) * (IDIM + 1) + IDIM];
        }
        creg0 = c0[(size_t)bglob * HDIM + hcol0];
        creg1 = c0[(size_t)bglob * HDIM + hcol0 + 1];
        // publish h(0): parity 0, tag 1
        ST_A64(hgrp + 0 * 1024 + b * 256 + r * 8 + cp,
               (1ULL << 32) | (u64)pack2(h0[(size_t)bglob * HDIM + hcol0],
                                         h0[(size_t)bglob * HDIM + hcol0 + 1]));
    } else {
        #pragma unroll
        for (int gt = 0; gt < 4; ++gt){
            bs2[gt][0] = bs2[gt][1] = wt2[gt][0] = wt2[gt][1] = 0.f;
        }
    }

    // ---- consumer stage indices: thread stages words tid*4..tid*4+3 ----
    const int sb = (tid * 4) >> 8;          // batch row 0..3
    const int sw = (tid * 4) & 255;         // word within row

    // ---- A-loader lanes: row = batch lb (MFMA rows 4..15 junk) ----
    const bool ldr = (l15 < 4);
    const int lb = l15 & 3;
    const int lbg = g * BPG + lb;

    // ---- x prefetch: x(0)->xe, x(1)->xo (bf16, registers) ----
    bfrag xe[KX], xo[KX];
    #pragma unroll
    for (int j = 0; j < KX; ++j){
        bfrag zv; 
        #pragma unroll
        for (int q = 0; q < 8; ++q) zv[q] = 0;
        xe[j] = zv; xo[j] = zv;
    }
    if (ldr){
        #pragma unroll
        for (int j = 0; j < KX; ++j){
            const float4* p0 = reinterpret_cast<const float4*>(
                x + ((size_t)0 * BTOT + lbg) * IDIM + j * 32 + kgrp * 8);
            const float4* p1 = reinterpret_cast<const float4*>(
                x + ((size_t)1 * BTOT + lbg) * IDIM + j * 32 + kgrp * 8);
            const float4 a0 = p0[0], a1 = p0[1], b0 = p1[0], b1 = p1[1];
            bfrag v;
            v[0]=(short)f2bf(a0.x); v[1]=(short)f2bf(a0.y);
            v[2]=(short)f2bf(a0.z); v[3]=(short)f2bf(a0.w);
            v[4]=(short)f2bf(a1.x); v[5]=(short)f2bf(a1.y);
            v[6]=(short)f2bf(a1.z); v[7]=(short)f2bf(a1.w);
            xe[j] = v;
            bfrag w;
            w[0]=(short)f2bf(b0.x); w[1]=(short)f2bf(b0.y);
            w[2]=(short)f2bf(b0.z); w[3]=(short)f2bf(b0.w);
            w[4]=(short)f2bf(b1.x); w[5]=(short)f2bf(b1.y);
            w[6]=(short)f2bf(b1.z); w[7]=(short)f2bf(b1.w);
            xo[j] = w;
        }
    }
    float tpf0 = 0.f, tpf1 = 0.f;
    if (gth){
        tpf0 = tim[(size_t)0 * BTOT + bglob];
        tpf1 = tim[(size_t)1 * BTOT + bglob];
    }

    for (int t = 0; t < TS; t += 2){
        LSTM_STEP(t,     xe, tpf0);
        LSTM_STEP(t + 1, xo, tpf1);
    }
}

extern "C" void kernel_launch(void* const* d_in, const int* in_sizes, int n_in,
                              void* d_out, int out_size, void* d_ws, size_t ws_size,
                              hipStream_t stream) {
    const float* x    = (const float*)d_in[0];
    const float* tim  = (const float*)d_in[1];
    const float* Wih  = (const float*)d_in[2];
    const float* Whh  = (const float*)d_in[3];
    const float* bias = (const float*)d_in[4];
    const float* h0   = (const float*)d_in[5];
    const float* c0   = (const float*)d_in[6];

    u64* hbuf = (u64*)d_ws;

    // tags must start != any wanted tag every launch (graph replays included)
    hipMemsetAsync(d_ws, 0, GRPS * 2 * 1024 * sizeof(u64), stream);

    lstm_grp<<<GRPS * WPG, NTHR, 0, stream>>>(x, tim, Wih, Whh, bias, h0, c0,
                                              (float*)d_out, hbuf);
}